// Round 6
// baseline (1683.979 us; speedup 1.0000x reference)
//
#include <hip/hip_runtime.h>

// WasserIndexGen: Wasserstein barycenter Sinkhorn (N=4096, NBB=64, <=30 iters).
// Round-5 (resubmit after infra timeout; logic re-audited): full-K stripe
// GEMMs with fused epilogues. Block beta owns output rows [16b,16b+16).
// k_fwd1 = C@u + div (writes rT bf16). k_fwd2 = C^T@r + rowwise
// (v,yhat,u,err) + ticket commit. No split-K partials buffer, 2 dispatches
// per iteration. C and C^T materialized bf16 once by k_cgen (64 MB,
// L3-resident). MFMA fragment addressing identical to the hardware-verified
// round-4 kernel (absmax 0.0). Loop control device-side, double-buffered
// active flags; captured sequence is data-independent.
//
// ws (~67 MB): Cbf bf16[4096][4096], CTbf bf16[4096][4096], uT/rT bf16
// [64][4096], u/v f32[4096][64], yh/yhn f32[4096], S[64], Spart[256*4].

typedef __attribute__((ext_vector_type(8))) short bf16x8;
typedef __attribute__((ext_vector_type(8))) unsigned short u16x8;
typedef __attribute__((ext_vector_type(4))) float f32x4;

constexpr int NV    = 4096;
constexpr int NBB_  = 64;
constexpr int ITERS = 30;

__device__ __forceinline__ bool finitef(float x) {
  return __builtin_fabsf(x) <= 3.402823466e38f;  // false for NaN/inf
}

__device__ __forceinline__ unsigned short f2bf(float x) {  // RNE f32->bf16
  unsigned int u = __builtin_bit_cast(unsigned int, x);
  return (unsigned short)((u + 0x7fffu + ((u >> 16) & 1u)) >> 16);
}

// ---------------- setup: iterates + control scalars --------------------------
__global__ void k_setup(float* __restrict__ u, float* __restrict__ v,
                        unsigned short* __restrict__ uT, float* __restrict__ yh,
                        float* __restrict__ S) {
  const int gid = blockIdx.x * 256 + threadIdx.x;  // 16384 threads
  for (int i = gid; i < NV * NBB_; i += 16384) {
    u[i] = 1.0f; v[i] = 1.0f; uT[i] = 0x3F80;      // bf16(1.0)
  }
  for (int i = gid; i < NV; i += 16384) yh[i] = 0.0f;
  if (gid == 0) {
    int* Si = (int*)S;
    S[0]  = 1.0f;          // err
    Si[1] = 0;             // cpt
    Si[2] = 0;             // broke
    Si[3] = 1; Si[4] = 0;  // active[slot]
    Si[5] = 0; Si[6] = 0;  // badCu[slot]
    Si[7] = 0; Si[8] = 0;  // nonfin[slot]
    for (int q = 16; q < 16 + ITERS; ++q) Si[q] = 0;  // tickets[it]
  }
}

// ---------------- Cbf = bf16(exp(-M/reg)), CTbf = Cbf^T ---------------------
__global__ void k_cgen(const float* __restrict__ M, const float* __restrict__ regp,
                       unsigned short* __restrict__ Cb,
                       unsigned short* __restrict__ CTb) {
  __shared__ float tile[64][65];
  const int jb = (blockIdx.x & 63) * 64;
  const int ib = (blockIdx.x >> 6) * 64;
  const float ninv = -1.0f / regp[0];
  const int t = threadIdx.x;
#pragma unroll
  for (int s = 0; s < 4; ++s) {
    const int l = s * 256 + t;
    const int r = l >> 4, c4 = l & 15;
    const float4 m4 = *(const float4*)&M[(size_t)(ib + r) * NV + jb + c4 * 4];
    float4 e4;
    e4.x = __expf(m4.x * ninv);
    e4.y = __expf(m4.y * ninv);
    e4.z = __expf(m4.z * ninv);
    e4.w = __expf(m4.w * ninv);
    ushort4 o;
    o.x = f2bf(e4.x); o.y = f2bf(e4.y); o.z = f2bf(e4.z); o.w = f2bf(e4.w);
    *(ushort4*)&Cb[(size_t)(ib + r) * NV + jb + c4 * 4] = o;
    *(float4*)&tile[r][c4 * 4] = e4;
  }
  __syncthreads();
#pragma unroll
  for (int s = 0; s < 4; ++s) {
    const int l = s * 256 + t;
    const int r = l >> 4, c4 = l & 15;
    ushort4 o;
    o.x = f2bf(tile[c4 * 4 + 0][r]);
    o.y = f2bf(tile[c4 * 4 + 1][r]);
    o.z = f2bf(tile[c4 * 4 + 2][r]);
    o.w = f2bf(tile[c4 * 4 + 3][r]);
    *(ushort4*)&CTb[(size_t)(jb + r) * NV + ib + c4 * 4] = o;
  }
}

// ---------------- fwd1: Cu stripe = C[16 rows] @ u, then r = b/Cu -----------
// grid 256 x 1024 (16 waves). Wave w: coltile ct=w&3, k-slice ks=w>>2 (1024).
// Frag addressing identical to round-4 verified layout:
//   A lane(lr,lg): row=lr, k = base+lg*8..+8 ; B: col=lr (of coltile), same k.
//   D: col=lr, row=lg*4+q.
__global__ __launch_bounds__(1024) void k_fwd1(
    const unsigned short* __restrict__ Cb, const unsigned short* __restrict__ uT,
    const float* __restrict__ b, unsigned short* __restrict__ rT,
    int* __restrict__ badflag, const int* __restrict__ act) {
  if (*act == 0) return;
  __shared__ f32x4 red4[16][64];  // 16 KB
  const int R = blockIdx.x * 16;
  const int t = threadIdx.x, w = t >> 6, lane = t & 63;
  const int lr = lane & 15, lg = lane >> 4;
  const int ct = w & 3, ks = w >> 2;
  const unsigned short* Ap = Cb + (size_t)(R + lr) * NV + ks * 1024 + lg * 8;
  const unsigned short* Bp = uT + (size_t)(ct * 16 + lr) * NV + ks * 1024 + lg * 8;
  f32x4 acc = {0.f, 0.f, 0.f, 0.f};
#pragma unroll 8
  for (int kk = 0; kk < 1024; kk += 32) {
    const bf16x8 af = *(const bf16x8*)(Ap + kk);
    const bf16x8 bf = *(const bf16x8*)(Bp + kk);
    acc = __builtin_amdgcn_mfma_f32_16x16x32_bf16(af, bf, acc, 0, 0, 0);
  }
  red4[w][lane] = acc;
  __syncthreads();
  if (w < 4) {
    f32x4 cu = red4[w][lane];
    cu += red4[w + 4][lane];
    cu += red4[w + 8][lane];
    cu += red4[w + 12][lane];
    bool bad = false;
    float rq[4];
#pragma unroll
    for (int q = 0; q < 4; ++q) {
      const float cuq = cu[q];
      const float bq  = b[(R + lg * 4 + q) * NBB_ + w * 16 + lr];
      bad |= (cuq == 0.0f);
      rq[q] = bq / cuq;
    }
    ushort4 rr;
    rr.x = f2bf(rq[0]); rr.y = f2bf(rq[1]); rr.z = f2bf(rq[2]); rr.w = f2bf(rq[3]);
    *(ushort4*)&rT[(size_t)(w * 16 + lr) * NV + R + lg * 4] = rr;
    if (bad) atomicOr(badflag, 1);
  }
}

// ---------------- fwd2: Va stripe = C^T[16 rows] @ r + rowwise + commit -----
__global__ __launch_bounds__(1024) void k_fwd2(
    const unsigned short* __restrict__ CTb, const unsigned short* __restrict__ rT,
    const float* __restrict__ lbd, float* __restrict__ u, float* __restrict__ v,
    unsigned short* __restrict__ uT, float* __restrict__ yh,
    float* __restrict__ yhn, float* __restrict__ Spart, float* __restrict__ S,
    int it) {
  int* Si = (int*)S;
  const int slot = it & 1;
  if (Si[3 + slot] == 0) {
    if (blockIdx.x == 0 && threadIdx.x == 0) Si[3 + (slot ^ 1)] = 0;
    return;
  }
  __shared__ f32x4 red4[16][64];
  __shared__ float yred[4][16];
  __shared__ float yhl[16];
  __shared__ float wred[4][4];
  __shared__ float cred[16][4];
  __shared__ int   flags[2];  // [0]=is-last-block, [1]=commit
  const int R = blockIdx.x * 16;
  const int t = threadIdx.x, w = t >> 6, lane = t & 63;
  const int lr = lane & 15, lg = lane >> 4;
  const int ct = w & 3, ks = w >> 2;
  const unsigned short* Ap = CTb + (size_t)(R + lr) * NV + ks * 1024 + lg * 8;
  const unsigned short* Bp = rT + (size_t)(ct * 16 + lr) * NV + ks * 1024 + lg * 8;
  f32x4 acc = {0.f, 0.f, 0.f, 0.f};
#pragma unroll 8
  for (int kk = 0; kk < 1024; kk += 32) {
    const bf16x8 af = *(const bf16x8*)(Ap + kk);
    const bf16x8 bf = *(const bf16x8*)(Bp + kk);
    acc = __builtin_amdgcn_mfma_f32_16x16x32_bf16(af, bf, acc, 0, 0, 0);
  }
  red4[w][lane] = acc;
  __syncthreads();
  f32x4 vv = {0.f, 0.f, 0.f, 0.f};
  if (w < 4) {
    vv = red4[w][lane];
    vv += red4[w + 4][lane];
    vv += red4[w + 8][lane];
    vv += red4[w + 12][lane];
    const float lb = lbd[w * 16 + lr];
    float p[4];
#pragma unroll
    for (int q = 0; q < 4; ++q) p[q] = lb * __logf(vv[q]);
#pragma unroll
    for (int o = 1; o < 16; o <<= 1) {
#pragma unroll
      for (int q = 0; q < 4; ++q) p[q] += __shfl_xor(p[q], o);
    }
    if (lr == 0) {
#pragma unroll
      for (int q = 0; q < 4; ++q) yred[w][lg * 4 + q] = p[q];
    }
  }
  __syncthreads();
  if (t < 16) {
    const float s   = yred[0][t] + yred[1][t] + yred[2][t] + yred[3][t];
    const float yhv = __expf(s);  // prod_j v^lbd_j
    yhl[t] = yhv;
    yhn[R + t] = yhv;
    if (!finitef(yhv)) atomicOr(&Si[7 + slot], 1);
  }
  __syncthreads();
  if (w < 4) {
    float s0 = 0.f, s1 = 0.f, s2 = 0.f, s3 = 0.f;
    bool bad = false;
    float un4[4];
#pragma unroll
    for (int q = 0; q < 4; ++q) {
      const int   row = lg * 4 + q;
      const float yhv = yhl[row];
      const float un  = yhv / vv[q];
      un4[q] = un;
      const int idx = (R + row) * NBB_ + w * 16 + lr;
      const float uo = u[idx], vo = v[idx];
      u[idx] = un;
      v[idx] = vv[q];
      const float du = un - uo, dv = vv[q] - vo;
      s0 += du * du; s1 += un * un; s2 += dv * dv; s3 += vv[q] * vv[q];
      bad |= !(finitef(un) && finitef(vv[q]));
    }
    ushort4 uu;
    uu.x = f2bf(un4[0]); uu.y = f2bf(un4[1]); uu.z = f2bf(un4[2]); uu.w = f2bf(un4[3]);
    *(ushort4*)&uT[(size_t)(w * 16 + lr) * NV + R + lg * 4] = uu;
    if (bad) atomicOr(&Si[7 + slot], 1);
#pragma unroll
    for (int o = 1; o < 64; o <<= 1) {
      s0 += __shfl_xor(s0, o); s1 += __shfl_xor(s1, o);
      s2 += __shfl_xor(s2, o); s3 += __shfl_xor(s3, o);
    }
    if (lane == 0) {
      wred[w][0] = s0; wred[w][1] = s1; wred[w][2] = s2; wred[w][3] = s3;
    }
  }
  __syncthreads();
  if (t == 0) {
#pragma unroll
    for (int c = 0; c < 4; ++c)
      Spart[blockIdx.x * 4 + c] =
          wred[0][c] + wred[1][c] + wred[2][c] + wred[3][c];
    __threadfence();
    flags[0] = (atomicAdd(&Si[16 + it], 1) == (int)gridDim.x - 1);
  }
  __syncthreads();
  if (!flags[0]) return;
  __threadfence();
  // ---- last block: reduce Spart[256][4] + control update + yhat commit ----
  {
    const int c = t & 3;
    float s = Spart[(t >> 2) * 4 + c];  // t>>2 in [0,256)
#pragma unroll
    for (int o = 4; o < 64; o <<= 1) s += __shfl_xor(s, o);
    if (lane < 4) cred[w][lane] = s;
  }
  __syncthreads();
  if (t == 0) {
    float q0 = 0.f, q1 = 0.f, q2 = 0.f, q3 = 0.f;
#pragma unroll
    for (int i = 0; i < 16; ++i) {
      q0 += cred[i][0]; q1 += cred[i][1]; q2 += cred[i][2]; q3 += cred[i][3];
    }
    const bool bad = (Si[5 + slot] | Si[7 + slot]) != 0;
    int com = 0;
    if (!bad) {
      const int cpt = Si[1];
      if (cpt % 10 == 0) S[0] = q0 / q1 + q2 / q3;  // err = lhs + rhs
      Si[1] = cpt + 1;
      com = 1;
    } else {
      Si[2] = 1;  // broke
    }
    const int ns = slot ^ 1;
    Si[3 + ns] = (S[0] > 1e-9f && Si[1] < ITERS && Si[2] == 0) ? 1 : 0;
    Si[5 + ns] = 0;
    Si[7 + ns] = 0;
    flags[1] = com;
  }
  __syncthreads();
  if (flags[1])
    for (int i = t; i < NV; i += 1024) yh[i] = yhn[i];
}

// ---------------- out = sum((yhat - a)^2) -----------------------------------
__global__ void k_final(const float* __restrict__ yhat, const float* __restrict__ a,
                        float* __restrict__ out) {
  __shared__ float red[4];
  const int t = threadIdx.x;
  float s = 0.0f;
  for (int i = t; i < NV; i += 256) {
    const float d = yhat[i] - a[i];
    s = fmaf(d, d, s);
  }
#pragma unroll
  for (int o = 32; o > 0; o >>= 1) s += __shfl_xor(s, o);
  if ((t & 63) == 0) red[t >> 6] = s;
  __syncthreads();
  if (t == 0) out[0] = red[0] + red[1] + red[2] + red[3];
}

extern "C" void kernel_launch(void* const* d_in, const int* in_sizes, int n_in,
                              void* d_out, int out_size, void* d_ws, size_t ws_size,
                              hipStream_t stream) {
  const float* a   = (const float*)d_in[0];
  const float* M   = (const float*)d_in[1];
  const float* b   = (const float*)d_in[2];
  const float* lbd = (const float*)d_in[3];
  const float* reg = (const float*)d_in[4];
  float* out = (float*)d_out;

  char* wsb = (char*)d_ws;
  size_t off = 0;
  auto alloc = [&](size_t bytes) -> void* {
    void* p = wsb + off;
    off += (bytes + 255) & ~(size_t)255;
    return p;
  };
  unsigned short* Cbf   = (unsigned short*)alloc(2 * (size_t)NV * NV);
  unsigned short* CTbf  = (unsigned short*)alloc(2 * (size_t)NV * NV);
  unsigned short* uT    = (unsigned short*)alloc(2 * (size_t)NV * NBB_);
  unsigned short* rT    = (unsigned short*)alloc(2 * (size_t)NV * NBB_);
  float*          u     = (float*)alloc(sizeof(float) * (size_t)NV * NBB_);
  float*          v     = (float*)alloc(sizeof(float) * (size_t)NV * NBB_);
  float*          yh    = (float*)alloc(sizeof(float) * NV);
  float*          yhn   = (float*)alloc(sizeof(float) * NV);
  float*          S     = (float*)alloc(sizeof(float) * 64);
  float*          Spart = (float*)alloc(sizeof(float) * 256 * 4);
  int* Si = (int*)S;

  k_setup<<<dim3(64), dim3(256), 0, stream>>>(u, v, uT, yh, S);
  k_cgen<<<dim3(4096), dim3(256), 0, stream>>>(M, reg, Cbf, CTbf);

  for (int it = 0; it < ITERS; ++it) {
    const int slot = it & 1;
    const int* act = (const int*)(Si + 3 + slot);
    k_fwd1<<<dim3(256), dim3(1024), 0, stream>>>(Cbf, uT, b, rT, Si + 5 + slot, act);
    k_fwd2<<<dim3(256), dim3(1024), 0, stream>>>(CTbf, rT, lbd, u, v, uT, yh,
                                                 yhn, Spart, S, it);
  }

  k_final<<<dim3(1), dim3(256), 0, stream>>>(yh, a, out);
}

// Round 7
// 1237.057 us; speedup vs baseline: 1.3613x; 1.3613x over previous
//
#include <hip/hip_runtime.h>

// WasserIndexGen: Wasserstein barycenter Sinkhorn (N=4096, NBB=64, <=30 iters).
// Round-7: fix round-6's GEMM core. Waves own K-SLICES (not col-tiles), so C
// is read exactly once per GEMM (round-6 read it 4x redundantly). Explicit
// 3-deep software-pipelined register prefetch (static indices) keeps ~15
// loads in flight per wave. 2 fused dispatches/iter as before:
// k_fwd1 = C@u + div (writes rT bf16); k_fwd2 = C^T@r + rowwise + ticket
// commit. Epilogue/control machinery identical to the round-6 kernel that
// passed with absmax 0.0 (re-indexed for 512 threads / 8 waves).
//
// ws (~67 MB): Cbf bf16[4096][4096], CTbf bf16[4096][4096], uT/rT bf16
// [64][4096], u/v f32[4096][64], yh/yhn f32[4096], S[64], Spart[256*4].

typedef __attribute__((ext_vector_type(8))) short bf16x8;
typedef __attribute__((ext_vector_type(4))) float f32x4;

constexpr int NV    = 4096;
constexpr int NBB_  = 64;
constexpr int ITERS = 30;

__device__ __forceinline__ bool finitef(float x) {
  return __builtin_fabsf(x) <= 3.402823466e38f;  // false for NaN/inf
}

__device__ __forceinline__ unsigned short f2bf(float x) {  // RNE f32->bf16
  unsigned int u = __builtin_bit_cast(unsigned int, x);
  return (unsigned short)((u + 0x7fffu + ((u >> 16) & 1u)) >> 16);
}

// ---------------- setup: iterates + control scalars --------------------------
__global__ void k_setup(float* __restrict__ u, float* __restrict__ v,
                        unsigned short* __restrict__ uT, float* __restrict__ yh,
                        float* __restrict__ S) {
  const int gid = blockIdx.x * 256 + threadIdx.x;  // 16384 threads
  for (int i = gid; i < NV * NBB_; i += 16384) {
    u[i] = 1.0f; v[i] = 1.0f; uT[i] = 0x3F80;      // bf16(1.0)
  }
  for (int i = gid; i < NV; i += 16384) yh[i] = 0.0f;
  if (gid == 0) {
    int* Si = (int*)S;
    S[0]  = 1.0f;          // err
    Si[1] = 0;             // cpt
    Si[2] = 0;             // broke
    Si[3] = 1; Si[4] = 0;  // active[slot]
    Si[5] = 0; Si[6] = 0;  // badCu[slot]
    Si[7] = 0; Si[8] = 0;  // nonfin[slot]
    for (int q = 16; q < 16 + ITERS; ++q) Si[q] = 0;  // tickets[it]
  }
}

// ---------------- Cbf = bf16(exp(-M/reg)), CTbf = Cbf^T ---------------------
__global__ void k_cgen(const float* __restrict__ M, const float* __restrict__ regp,
                       unsigned short* __restrict__ Cb,
                       unsigned short* __restrict__ CTb) {
  __shared__ float tile[64][65];
  const int jb = (blockIdx.x & 63) * 64;
  const int ib = (blockIdx.x >> 6) * 64;
  const float ninv = -1.0f / regp[0];
  const int t = threadIdx.x;
#pragma unroll
  for (int s = 0; s < 4; ++s) {
    const int l = s * 256 + t;
    const int r = l >> 4, c4 = l & 15;
    const float4 m4 = *(const float4*)&M[(size_t)(ib + r) * NV + jb + c4 * 4];
    float4 e4;
    e4.x = __expf(m4.x * ninv);
    e4.y = __expf(m4.y * ninv);
    e4.z = __expf(m4.z * ninv);
    e4.w = __expf(m4.w * ninv);
    ushort4 o;
    o.x = f2bf(e4.x); o.y = f2bf(e4.y); o.z = f2bf(e4.z); o.w = f2bf(e4.w);
    *(ushort4*)&Cb[(size_t)(ib + r) * NV + jb + c4 * 4] = o;
    *(float4*)&tile[r][c4 * 4] = e4;
  }
  __syncthreads();
#pragma unroll
  for (int s = 0; s < 4; ++s) {
    const int l = s * 256 + t;
    const int r = l >> 4, c4 = l & 15;
    ushort4 o;
    o.x = f2bf(tile[c4 * 4 + 0][r]);
    o.y = f2bf(tile[c4 * 4 + 1][r]);
    o.z = f2bf(tile[c4 * 4 + 2][r]);
    o.w = f2bf(tile[c4 * 4 + 3][r]);
    *(ushort4*)&CTb[(size_t)(jb + r) * NV + ib + c4 * 4] = o;
  }
}

// GEMM core (shared by fwd1/fwd2): block owns 16 output rows, wave w owns
// k-slice [w*512, w*512+512), computes ALL 4 col-tiles (A read once).
// 3-deep register software pipeline; all indices static after unroll.
// Result: red4[w][ct][lane] in LDS; caller reduces the 8 k-slices.
#define GEMM_CORE(Abase, Bbase, red4)                                          \
  {                                                                            \
    const unsigned short* Ap = (Abase) + (size_t)(R + lr) * NV + w * 512 + lg * 8; \
    const unsigned short* Bp = (Bbase) + (size_t)lr * NV + w * 512 + lg * 8;   \
    f32x4 acc[4] = {};                                                         \
    bf16x8 abuf[3];                                                            \
    bf16x8 bbuf[3][4];                                                         \
    _Pragma("unroll")                                                          \
    for (int p = 0; p < 3; ++p) {                                              \
      abuf[p] = *(const bf16x8*)(Ap + 32 * p);                                 \
      _Pragma("unroll")                                                        \
      for (int ct = 0; ct < 4; ++ct)                                           \
        bbuf[p][ct] = *(const bf16x8*)(Bp + (size_t)ct * 16 * NV + 32 * p);    \
    }                                                                          \
    _Pragma("unroll")                                                          \
    for (int i = 0; i < 16; ++i) {                                             \
      const int sl = i % 3;                                                    \
      _Pragma("unroll")                                                        \
      for (int ct = 0; ct < 4; ++ct)                                           \
        acc[ct] = __builtin_amdgcn_mfma_f32_16x16x32_bf16(abuf[sl],            \
                                                          bbuf[sl][ct],        \
                                                          acc[ct], 0, 0, 0);   \
      if (i + 3 < 16) {                                                        \
        abuf[sl] = *(const bf16x8*)(Ap + 32 * (i + 3));                        \
        _Pragma("unroll")                                                      \
        for (int ct = 0; ct < 4; ++ct)                                         \
          bbuf[sl][ct] =                                                       \
              *(const bf16x8*)(Bp + (size_t)ct * 16 * NV + 32 * (i + 3));      \
      }                                                                        \
    }                                                                          \
    _Pragma("unroll")                                                          \
    for (int ct = 0; ct < 4; ++ct) red4[w][ct][lane] = acc[ct];                \
  }

// ---------------- fwd1: Cu stripe = C[16 rows] @ u, then r = b/Cu -----------
// grid 256 x 512 (8 waves). D frag: col = ct*16+lr, row = lg*4+q.
__global__ __launch_bounds__(512, 2) void k_fwd1(
    const unsigned short* __restrict__ Cb, const unsigned short* __restrict__ uT,
    const float* __restrict__ b, unsigned short* __restrict__ rT,
    int* __restrict__ badflag, const int* __restrict__ act) {
  if (*act == 0) return;
  __shared__ f32x4 red4[8][4][64];  // 32 KB
  const int R = blockIdx.x * 16;
  const int t = threadIdx.x, w = t >> 6, lane = t & 63;
  const int lr = lane & 15, lg = lane >> 4;
  GEMM_CORE(Cb, uT, red4)
  __syncthreads();
  if (w < 4) {
    const int ct = w;
    f32x4 cu = red4[0][ct][lane];
#pragma unroll
    for (int j = 1; j < 8; ++j) cu += red4[j][ct][lane];
    bool bad = false;
    float rq[4];
#pragma unroll
    for (int q = 0; q < 4; ++q) {
      const float cuq = cu[q];
      const float bq  = b[(R + lg * 4 + q) * NBB_ + ct * 16 + lr];
      bad |= (cuq == 0.0f);
      rq[q] = bq / cuq;
    }
    ushort4 rr;
    rr.x = f2bf(rq[0]); rr.y = f2bf(rq[1]); rr.z = f2bf(rq[2]); rr.w = f2bf(rq[3]);
    *(ushort4*)&rT[(size_t)(ct * 16 + lr) * NV + R + lg * 4] = rr;
    if (bad) atomicOr(badflag, 1);
  }
}

// ---------------- fwd2: Va stripe = C^T[16 rows] @ r + rowwise + commit -----
__global__ __launch_bounds__(512, 2) void k_fwd2(
    const unsigned short* __restrict__ CTb, const unsigned short* __restrict__ rT,
    const float* __restrict__ lbd, float* __restrict__ u, float* __restrict__ v,
    unsigned short* __restrict__ uT, float* __restrict__ yh,
    float* __restrict__ yhn, float* __restrict__ Spart, float* __restrict__ S,
    int it) {
  int* Si = (int*)S;
  const int slot = it & 1;
  if (Si[3 + slot] == 0) {
    if (blockIdx.x == 0 && threadIdx.x == 0) Si[3 + (slot ^ 1)] = 0;
    return;
  }
  __shared__ f32x4 red4[8][4][64];  // 32 KB
  __shared__ float yred[4][16];
  __shared__ float yhl[16];
  __shared__ float wred[4][4];
  __shared__ float cred[8][4];
  __shared__ int   flags[2];  // [0]=is-last-block, [1]=commit
  const int R = blockIdx.x * 16;
  const int t = threadIdx.x, w = t >> 6, lane = t & 63;
  const int lr = lane & 15, lg = lane >> 4;
  GEMM_CORE(CTb, rT, red4)
  __syncthreads();
  f32x4 vv = {0.f, 0.f, 0.f, 0.f};
  if (w < 4) {
    vv = red4[0][w][lane];
#pragma unroll
    for (int j = 1; j < 8; ++j) vv += red4[j][w][lane];
    const float lb = lbd[w * 16 + lr];
    float p[4];
#pragma unroll
    for (int q = 0; q < 4; ++q) p[q] = lb * __logf(vv[q]);
#pragma unroll
    for (int o = 1; o < 16; o <<= 1) {
#pragma unroll
      for (int q = 0; q < 4; ++q) p[q] += __shfl_xor(p[q], o);
    }
    if (lr == 0) {
#pragma unroll
      for (int q = 0; q < 4; ++q) yred[w][lg * 4 + q] = p[q];
    }
  }
  __syncthreads();
  if (t < 16) {
    const float s   = yred[0][t] + yred[1][t] + yred[2][t] + yred[3][t];
    const float yhv = __expf(s);  // prod_j v^lbd_j
    yhl[t] = yhv;
    yhn[R + t] = yhv;
    if (!finitef(yhv)) atomicOr(&Si[7 + slot], 1);
  }
  __syncthreads();
  if (w < 4) {
    float s0 = 0.f, s1 = 0.f, s2 = 0.f, s3 = 0.f;
    bool bad = false;
    float un4[4];
#pragma unroll
    for (int q = 0; q < 4; ++q) {
      const int   row = lg * 4 + q;
      const float yhv = yhl[row];
      const float un  = yhv / vv[q];
      un4[q] = un;
      const int idx = (R + row) * NBB_ + w * 16 + lr;
      const float uo = u[idx], vo = v[idx];
      u[idx] = un;
      v[idx] = vv[q];
      const float du = un - uo, dv = vv[q] - vo;
      s0 += du * du; s1 += un * un; s2 += dv * dv; s3 += vv[q] * vv[q];
      bad |= !(finitef(un) && finitef(vv[q]));
    }
    ushort4 uu;
    uu.x = f2bf(un4[0]); uu.y = f2bf(un4[1]); uu.z = f2bf(un4[2]); uu.w = f2bf(un4[3]);
    *(ushort4*)&uT[(size_t)(w * 16 + lr) * NV + R + lg * 4] = uu;
    if (bad) atomicOr(&Si[7 + slot], 1);
#pragma unroll
    for (int o = 1; o < 64; o <<= 1) {
      s0 += __shfl_xor(s0, o); s1 += __shfl_xor(s1, o);
      s2 += __shfl_xor(s2, o); s3 += __shfl_xor(s3, o);
    }
    if (lane == 0) {
      wred[w][0] = s0; wred[w][1] = s1; wred[w][2] = s2; wred[w][3] = s3;
    }
  }
  __syncthreads();
  if (t == 0) {
#pragma unroll
    for (int c = 0; c < 4; ++c)
      Spart[blockIdx.x * 4 + c] =
          wred[0][c] + wred[1][c] + wred[2][c] + wred[3][c];
    __threadfence();
    flags[0] = (atomicAdd(&Si[16 + it], 1) == (int)gridDim.x - 1);
  }
  __syncthreads();
  if (!flags[0]) return;
  __threadfence();
  // ---- last block: reduce Spart[256][4] + control update + yhat commit ----
  {
    const int c   = t & 3;
    const int idx = t >> 2;  // 0..127; fold 256 blocks in two halves
    float s = Spart[idx * 4 + c] + Spart[(idx + 128) * 4 + c];
#pragma unroll
    for (int o = 4; o < 64; o <<= 1) s += __shfl_xor(s, o);
    if (lane < 4) cred[w][lane] = s;
  }
  __syncthreads();
  if (t == 0) {
    float q0 = 0.f, q1 = 0.f, q2 = 0.f, q3 = 0.f;
#pragma unroll
    for (int i = 0; i < 8; ++i) {
      q0 += cred[i][0]; q1 += cred[i][1]; q2 += cred[i][2]; q3 += cred[i][3];
    }
    const bool bad = (Si[5 + slot] | Si[7 + slot]) != 0;
    int com = 0;
    if (!bad) {
      const int cpt = Si[1];
      if (cpt % 10 == 0) S[0] = q0 / q1 + q2 / q3;  // err = lhs + rhs
      Si[1] = cpt + 1;
      com = 1;
    } else {
      Si[2] = 1;  // broke
    }
    const int ns = slot ^ 1;
    Si[3 + ns] = (S[0] > 1e-9f && Si[1] < ITERS && Si[2] == 0) ? 1 : 0;
    Si[5 + ns] = 0;
    Si[7 + ns] = 0;
    flags[1] = com;
  }
  __syncthreads();
  if (flags[1])
    for (int i = t; i < NV; i += 512) yh[i] = yhn[i];
}

// ---------------- out = sum((yhat - a)^2) -----------------------------------
__global__ void k_final(const float* __restrict__ yhat, const float* __restrict__ a,
                        float* __restrict__ out) {
  __shared__ float red[4];
  const int t = threadIdx.x;
  float s = 0.0f;
  for (int i = t; i < NV; i += 256) {
    const float d = yhat[i] - a[i];
    s = fmaf(d, d, s);
  }
#pragma unroll
  for (int o = 32; o > 0; o >>= 1) s += __shfl_xor(s, o);
  if ((t & 63) == 0) red[t >> 6] = s;
  __syncthreads();
  if (t == 0) out[0] = red[0] + red[1] + red[2] + red[3];
}

extern "C" void kernel_launch(void* const* d_in, const int* in_sizes, int n_in,
                              void* d_out, int out_size, void* d_ws, size_t ws_size,
                              hipStream_t stream) {
  const float* a   = (const float*)d_in[0];
  const float* M   = (const float*)d_in[1];
  const float* b   = (const float*)d_in[2];
  const float* lbd = (const float*)d_in[3];
  const float* reg = (const float*)d_in[4];
  float* out = (float*)d_out;

  char* wsb = (char*)d_ws;
  size_t off = 0;
  auto alloc = [&](size_t bytes) -> void* {
    void* p = wsb + off;
    off += (bytes + 255) & ~(size_t)255;
    return p;
  };
  unsigned short* Cbf   = (unsigned short*)alloc(2 * (size_t)NV * NV);
  unsigned short* CTbf  = (unsigned short*)alloc(2 * (size_t)NV * NV);
  unsigned short* uT    = (unsigned short*)alloc(2 * (size_t)NV * NBB_);
  unsigned short* rT    = (unsigned short*)alloc(2 * (size_t)NV * NBB_);
  float*          u     = (float*)alloc(sizeof(float) * (size_t)NV * NBB_);
  float*          v     = (float*)alloc(sizeof(float) * (size_t)NV * NBB_);
  float*          yh    = (float*)alloc(sizeof(float) * NV);
  float*          yhn   = (float*)alloc(sizeof(float) * NV);
  float*          S     = (float*)alloc(sizeof(float) * 64);
  float*          Spart = (float*)alloc(sizeof(float) * 256 * 4);
  int* Si = (int*)S;

  k_setup<<<dim3(64), dim3(256), 0, stream>>>(u, v, uT, yh, S);
  k_cgen<<<dim3(4096), dim3(256), 0, stream>>>(M, reg, Cbf, CTbf);

  for (int it = 0; it < ITERS; ++it) {
    const int slot = it & 1;
    const int* act = (const int*)(Si + 3 + slot);
    k_fwd1<<<dim3(256), dim3(512), 0, stream>>>(Cbf, uT, b, rT, Si + 5 + slot, act);
    k_fwd2<<<dim3(256), dim3(512), 0, stream>>>(CTbf, rT, lbd, u, v, uT, yh,
                                                yhn, Spart, S, it);
  }

  k_final<<<dim3(1), dim3(256), 0, stream>>>(yh, a, out);
}